// Round 3
// baseline (114.344 us; speedup 1.0000x reference)
//
#include <hip/hip_runtime.h>
#include <math.h>

#define HH 128
#define WW 128
#define NG 2048
#define DIMV 768
#define PIX (HH * WW)
#define A_MIN (1.0f / 255.0f)
#define TPX 8            // tile width (px)
#define TPY 2            // tile height (px)
#define MAXS 768         // compacted survivor capacity (worst-case est. ~100)
#define TWO_PI 6.28318530717958647692f

// ---------------------------------------------------------------------------
// K1: raster. 1024 blocks (4/CU, 16 waves/CU), one 8x2 tile each.
//  Phase A+B fused: per gaussian compute cheap cull triple (gx,gy,r2) --
//  trace(cov)=s0^2+s1^2 is rotation-invariant so no sin/cos -- test vs tile
//  rect; only survivors (~30/tile) compute the full conic + load colors,
//  written compacted into LDS. Bound is exact-conservative vs the
//  reference's alpha>=1/255 cutoff: sigma >= |d|^2/(2*lmax), lmax < trace.
//  Phase C: 16-way k-split (4 waves x 4 sub-k), 16 px/tile, 1 px per 4 lanes;
//  consecutive-k float4 LDS reads are bank-disjoint quarter-wave broadcasts.
//  Phase D: reduce 16 partials/px, clip, store img planes to ws.
// ---------------------------------------------------------------------------
__global__ __launch_bounds__(256, 4) void raster_kernel(
    const float* __restrict__ xyz, const float* __restrict__ scaling,
    const float* __restrict__ rotation, const float* __restrict__ features,
    const float* __restrict__ opacity, float* __restrict__ img)
{
    __shared__ float4 sQ0[MAXS];        // (A/2, B, C/2, op)
    __shared__ float4 sQ1[MAXS];        // (gx, gy, f0, f1)
    __shared__ float2 sQ2[MAXS];        // (f2, pad)
    __shared__ float  s_red[16 * 16 * 3];
    __shared__ int    s_cnt;

    int tid = threadIdx.x;
    int px0 = (blockIdx.x & 15) * TPX;
    int py0 = (blockIdx.x >> 4) * TPY;

    if (tid == 0) s_cnt = 0;
    __syncthreads();

    // ---- Phase A+B: cull all gaussians vs tile rect; survivors -> compact LDS
    {
        float x0 = px0 + 0.5f, x1 = px0 + TPX - 0.5f;
        float y0 = py0 + 0.5f, y1 = py0 + TPY - 0.5f;
        for (int g = tid; g < NG; g += 256) {
            float2 xz = ((const float2*)xyz)[g];
            float2 sc = ((const float2*)scaling)[g];
            float rt = rotation[g];
            float op = opacity[g];
            float e2x = __expf(2.0f * xz.x);
            float gx = (e2x / (e2x + 1.0f)) * (float)WW;   // 0.5*(tanh+1)*W
            float e2y = __expf(2.0f * xz.y);
            float gy = (e2y / (e2y + 1.0f)) * (float)HH;
            float s0 = fabsf(sc.x + 0.5f);
            float s1 = fabsf(sc.y + 0.5f);
            float tr = s0 * s0 + s1 * s1;                  // == cxx + cyy
            float L = __logf(255.0f * op);
            float r2 = (L > 0.0f) ? 2.0f * L * tr * 1.0002f + 1e-3f : -1.0f;
            float ddx = fmaxf(fmaxf(x0 - gx, gx - x1), 0.0f);
            float ddy = fmaxf(fmaxf(y0 - gy, gy - y1), 0.0f);
            if (ddx * ddx + ddy * ddy <= r2) {
                int pos = atomicAdd(&s_cnt, 1);
                if (pos < MAXS) {
                    float th = TWO_PI / (1.0f + __expf(-rt));
                    float sn = __sinf(th), cs = __cosf(th);
                    float a = cs * s0, b = -sn * s1, d = sn * s0, e = cs * s1;
                    float cxx = a * a + b * b;
                    float cxy = a * d + b * e;
                    float cyy = d * d + e * e;
                    float inv = 1.0f / (cxx * cyy - cxy * cxy); // det >= 1/16
                    sQ0[pos] = make_float4(0.5f * cyy * inv, -cxy * inv,
                                           0.5f * cxx * inv, op);
                    sQ1[pos] = make_float4(gx, gy, features[3 * g + 0],
                                           features[3 * g + 1]);
                    sQ2[pos] = make_float2(features[3 * g + 2], 0.0f);
                }
            }
        }
    }
    __syncthreads();
    int cnt = min(s_cnt, MAXS);

    int lane = tid & 63, wv = tid >> 6;
    int px = lane & 15;                 // pixel within 8x2 tile
    int ks = wv * 4 + (lane >> 4);      // k-split lane group: 0..15
    float pxf = px0 + (px & 7) + 0.5f;
    float pyf = py0 + (px >> 3) + 0.5f;

    // ---- Phase C: alpha-weighted color accumulation (16-way k-split)
    float ar = 0.0f, ag = 0.0f, ab = 0.0f;
    for (int k = ks; k < cnt; k += 16) {
        float4 a0 = sQ0[k];
        float4 a1 = sQ1[k];
        float2 a2 = sQ2[k];
        float dx = a1.x - pxf, dy = a1.y - pyf;
        float sig = fmaf(a0.y * dx, dy, fmaf(a0.x * dx, dx, a0.z * dy * dy));
        float al = fminf(0.999f, a0.w * __expf(-sig));
        al = (sig < 0.0f || al < A_MIN) ? 0.0f : al;
        ar = fmaf(al, a1.z, ar);
        ag = fmaf(al, a1.w, ag);
        ab = fmaf(al, a2.x, ab);
    }
    int ri = (ks * 16 + px) * 3;
    s_red[ri + 0] = ar;
    s_red[ri + 1] = ag;
    s_red[ri + 2] = ab;
    __syncthreads();

    // ---- Phase D: reduce 16 partials per pixel, clip, store img planes
    if (tid < 16) {
        float sr = 0.0f, sg = 0.0f, sb = 0.0f;
        #pragma unroll
        for (int j = 0; j < 16; ++j) {
            int b = (j * 16 + tid) * 3;
            sr += s_red[b + 0];
            sg += s_red[b + 1];
            sb += s_red[b + 2];
        }
        int p = (py0 + (tid >> 3)) * WW + px0 + (tid & 7);
        img[p]           = fminf(1.0f, fmaxf(0.0f, sr));
        img[PIX + p]     = fminf(1.0f, fmaxf(0.0f, sg));
        img[2 * PIX + p] = fminf(1.0f, fmaxf(0.0f, sb));
    }
}

// ---------------------------------------------------------------------------
// K2: projection to 768 channels. 3072 blocks (12/CU): blockIdx = grp*16+seg,
// grp -> 4 consecutive channels, seg -> 1024-pixel span. Pure write-bound:
// 3x float4 L2-resident img reads, 16 FMA, 4x float4 coalesced stores.
// ---------------------------------------------------------------------------
__global__ __launch_bounds__(256) void project_kernel(
    const float* __restrict__ img, const float* __restrict__ w_up,
    const float* __restrict__ b_up, float* __restrict__ out)
{
    int grp = blockIdx.x >> 4;
    int seg = blockIdx.x & 15;
    int p = seg * 1024 + threadIdx.x * 4;
    float4 r = *(const float4*)(img + p);
    float4 g = *(const float4*)(img + PIX + p);
    float4 b = *(const float4*)(img + 2 * PIX + p);
    int d0 = grp * 4;
    #pragma unroll
    for (int i = 0; i < 4; ++i) {
        int d = d0 + i;
        float w0 = w_up[3 * d + 0], w1 = w_up[3 * d + 1], w2 = w_up[3 * d + 2];
        float bb = b_up[d];
        float4 v;
        v.x = fmaf(w0, r.x, fmaf(w1, g.x, fmaf(w2, b.x, bb)));
        v.y = fmaf(w0, r.y, fmaf(w1, g.y, fmaf(w2, b.y, bb)));
        v.z = fmaf(w0, r.z, fmaf(w1, g.z, fmaf(w2, b.z, bb)));
        v.w = fmaf(w0, r.w, fmaf(w1, g.w, fmaf(w2, b.w, bb)));
        *(float4*)(out + (size_t)d * PIX + p) = v;
    }
}

extern "C" void kernel_launch(void* const* d_in, const int* in_sizes, int n_in,
                              void* d_out, int out_size, void* d_ws, size_t ws_size,
                              hipStream_t stream)
{
    // setup_inputs order: x(unused), xyz, scaling, rotation, features, opacity, w_up, b_up
    const float* xyz      = (const float*)d_in[1];
    const float* scaling  = (const float*)d_in[2];
    const float* rotation = (const float*)d_in[3];
    const float* features = (const float*)d_in[4];
    const float* opacity  = (const float*)d_in[5];
    const float* w_up     = (const float*)d_in[6];
    const float* b_up     = (const float*)d_in[7];
    float* out = (float*)d_out;
    float* img = (float*)d_ws;   // 3 planes of PIX floats (192 KB)

    raster_kernel<<<(WW / TPX) * (HH / TPY), 256, 0, stream>>>(
        xyz, scaling, rotation, features, opacity, img);
    project_kernel<<<(DIMV / 4) * 16, 256, 0, stream>>>(img, w_up, b_up, out);
}